// Round 1
// baseline (202.317 us; speedup 1.0000x reference)
//
#include <hip/hip_runtime.h>
#include <math.h>

#define N_X   20000
#define N_ELL 48
#define N_K   1024
#define N_TAU 600

// Kernel 1: one block per k. 256 threads = 4 waves; wave w handles tau = w, w+4, ...
// lane = ell (lanes 48..63 clamped, results discarded). Produces Tl[ell][k], El[ell][k].
__global__ __launch_bounds__(256) void tl_el_kernel(
    const float* __restrict__ k, const float* __restrict__ tau,
    const float* __restrict__ tau0p,
    const float* __restrict__ S0, const float* __restrict__ S1,
    const float* __restrict__ S2, const float* __restrict__ SE,
    const float* __restrict__ bx,
    const float* __restrict__ p0, const float* __restrict__ p1,
    const float* __restrict__ p2, const float* __restrict__ pe,
    float* __restrict__ Tl, float* __restrict__ El)
{
    const int kidx = blockIdx.x;
    const int tid  = threadIdx.x;
    const int wave = tid >> 6;
    const int lane = tid & 63;
    const int ell  = (lane < N_ELL) ? lane : (N_ELL - 1);

    const float kk    = k[kidx];
    const float tau0  = tau0p[0];
    const float xmin  = bx[0];
    const float xmax  = bx[N_X - 1];
    const float scale = (float)(N_X - 1) / (xmax - xmin);

    const float* Srow0 = S0 + (size_t)kidx * N_TAU;
    const float* Srow1 = S1 + (size_t)kidx * N_TAU;
    const float* Srow2 = S2 + (size_t)kidx * N_TAU;
    const float* SrowE = SE + (size_t)kidx * N_TAU;

    float accT = 0.0f, accE = 0.0f;

    for (int t = wave; t < N_TAU; t += 4) {
        float tt    = tau[t];
        float tprev = (t > 0)         ? tau[t - 1] : tt;
        float tnext = (t < N_TAU - 1) ? tau[t + 1] : tt;
        float wt    = 0.5f * (tnext - tprev);   // trapezoid weight for sample t

        float x   = kk * (tau0 - tt);
        float pos = (x - xmin) * scale;
        pos = fminf(fmaxf(pos, 0.0f), (float)(N_X - 1));
        int i0 = (int)floorf(pos);
        if (i0 > N_X - 2) i0 = N_X - 2;
        float w = pos - (float)i0;

        int base = i0 * N_ELL + ell;
        float y00 = p0[base], y01 = p0[base + N_ELL];
        float y10 = p1[base], y11 = p1[base + N_ELL];
        float y20 = p2[base], y21 = p2[base + N_ELL];
        float ye0 = pe[base], ye1 = pe[base + N_ELL];

        float a0 = fmaf(w, y01 - y00, y00);
        float a1 = fmaf(w, y11 - y10, y10);
        float a2 = fmaf(w, y21 - y20, y20);
        float ae = fmaf(w, ye1 - ye0, ye0);

        float s0 = Srow0[t], s1 = Srow1[t], s2 = Srow2[t], se = SrowE[t];

        float srcT = s0 * a0 + s1 * a1 + s2 * a2;
        accT = fmaf(wt, srcT, accT);
        accE = fmaf(wt, se * ae, accE);
    }

    __shared__ float redT[4][N_ELL];
    __shared__ float redE[4][N_ELL];
    if (lane < N_ELL) { redT[wave][lane] = accT; redE[wave][lane] = accE; }
    __syncthreads();
    if (tid < N_ELL) {
        float sT = (redT[0][tid] + redT[1][tid]) + (redT[2][tid] + redT[3][tid]);
        float sE = (redE[0][tid] + redE[1][tid]) + (redE[2][tid] + redE[3][tid]);
        Tl[tid * N_K + kidx] = sT;   // [ell][k] layout -> coalesced reads in kernel 2
        El[tid * N_K + kidx] = sE;
    }
}

// Kernel 2: one block per ell. Trapezoid over k with primordial-spectrum weight.
__global__ __launch_bounds__(256) void cl_kernel(
    const float* __restrict__ k,
    const float* __restrict__ Asp, const float* __restrict__ nsp,
    const float* __restrict__ Tl, const float* __restrict__ El,
    float* __restrict__ out)
{
    const int ell = blockIdx.x;
    const int tid = threadIdx.x;
    const float A_s = Asp[0];
    const float n_s = nsp[0];
    const float two_pi2 = 2.0f * (float)M_PI * (float)M_PI;

    float aTT = 0.0f, aEE = 0.0f, aTE = 0.0f;
    for (int i = tid; i < N_K; i += 256) {
        float kv    = k[i];
        float kprev = (i > 0)       ? k[i - 1] : kv;
        float knext = (i < N_K - 1) ? k[i + 1] : kv;
        float dkw   = 0.5f * (knext - kprev);            // trapezoid weight
        // w(k) = k^2 * P_R(k) = A_s (k/kp)^(ns-1) * 2 pi^2 / k
        float P  = A_s * powf(kv / 0.05f, n_s - 1.0f) * two_pi2 / kv;
        float ww = dkw * P;
        float tl = Tl[(size_t)ell * N_K + i];
        float el = El[(size_t)ell * N_K + i];
        aTT = fmaf(ww * tl, tl, aTT);
        aEE = fmaf(ww * el, el, aEE);
        aTE = fmaf(ww * tl, el, aTE);
    }

    // wave reduce (64 lanes) then cross-wave via LDS
    for (int off = 32; off > 0; off >>= 1) {
        aTT += __shfl_down(aTT, off, 64);
        aEE += __shfl_down(aEE, off, 64);
        aTE += __shfl_down(aTE, off, 64);
    }
    __shared__ float red[3][4];
    const int wave = tid >> 6, lane = tid & 63;
    if (lane == 0) { red[0][wave] = aTT; red[1][wave] = aEE; red[2][wave] = aTE; }
    __syncthreads();
    if (tid == 0) {
        const float c = 2.0f / (float)M_PI;
        out[0 * N_ELL + ell] = c * ((red[0][0] + red[0][1]) + (red[0][2] + red[0][3]));
        out[1 * N_ELL + ell] = c * ((red[1][0] + red[1][1]) + (red[1][2] + red[1][3]));
        out[2 * N_ELL + ell] = c * ((red[2][0] + red[2][1]) + (red[2][2] + red[2][3]));
    }
}

extern "C" void kernel_launch(void* const* d_in, const int* in_sizes, int n_in,
                              void* d_out, int out_size, void* d_ws, size_t ws_size,
                              hipStream_t stream) {
    const float* k    = (const float*)d_in[0];
    const float* tau  = (const float*)d_in[1];
    const float* tau0 = (const float*)d_in[2];
    const float* S0   = (const float*)d_in[3];
    const float* S1   = (const float*)d_in[4];
    const float* S2   = (const float*)d_in[5];
    const float* SE   = (const float*)d_in[6];
    const float* bx   = (const float*)d_in[7];
    const float* p0   = (const float*)d_in[8];
    const float* p1   = (const float*)d_in[9];
    const float* p2   = (const float*)d_in[10];
    const float* pe   = (const float*)d_in[11];
    const float* A_s  = (const float*)d_in[12];
    const float* n_s  = (const float*)d_in[13];
    float* out = (float*)d_out;

    float* Tl = (float*)d_ws;                    // [N_ELL][N_K]
    float* El = Tl + (size_t)N_ELL * N_K;        // [N_ELL][N_K]

    tl_el_kernel<<<N_K, 256, 0, stream>>>(k, tau, tau0, S0, S1, S2, SE, bx,
                                          p0, p1, p2, pe, Tl, El);
    cl_kernel<<<N_ELL, 256, 0, stream>>>(k, A_s, n_s, Tl, El, out);
}

// Round 2
// 156.981 us; speedup vs baseline: 1.2888x; 1.2888x over previous
//
#include <hip/hip_runtime.h>
#include <math.h>

#define N_X   20000
#define N_ELL 48
#define N_K   1024
#define N_TAU 600

// ---------------------------------------------------------------------------
// Repack the four [N_X][N_ELL] tables into interleaved [N_X][N_ELL]{p0,p1,p2,pe}
// float4 so the hot loop does 2 dwordx4 gathers instead of 8 scalar gathers.
__global__ __launch_bounds__(256) void repack_kernel(
    const float* __restrict__ p0, const float* __restrict__ p1,
    const float* __restrict__ p2, const float* __restrict__ pe,
    float4* __restrict__ P)
{
    const int total = N_X * N_ELL;
    for (int idx = blockIdx.x * blockDim.x + threadIdx.x; idx < total;
         idx += gridDim.x * blockDim.x) {
        P[idx] = make_float4(p0[idx], p1[idx], p2[idx], pe[idx]);
    }
}

// ---------------------------------------------------------------------------
// Packed main kernel: one block per k, 512 threads = 8 waves, lane = ell.
// wave w handles tau = w, w+8, ... (75 iterations each; 600 = 8*75).
__global__ __launch_bounds__(512, 8) void tl_el_packed(
    const float* __restrict__ k, const float* __restrict__ tau,
    const float* __restrict__ tau0p,
    const float* __restrict__ S0, const float* __restrict__ S1,
    const float* __restrict__ S2, const float* __restrict__ SE,
    const float* __restrict__ bx, const float4* __restrict__ P,
    float* __restrict__ Tl, float* __restrict__ El)
{
    const int kidx = blockIdx.x;
    const int tid  = threadIdx.x;
    const int wave = tid >> 6;
    const int lane = tid & 63;
    const int ell  = (lane < N_ELL) ? lane : (N_ELL - 1);

    // Preload tau grid + trapezoid weights into LDS (off the dependency chain).
    __shared__ float tau_s[N_TAU];
    __shared__ float wt_s[N_TAU];
    for (int t = tid; t < N_TAU; t += 512) {
        float tt = tau[t];
        float tp = (t > 0)         ? tau[t - 1] : tt;
        float tn = (t < N_TAU - 1) ? tau[t + 1] : tt;
        tau_s[t] = tt;
        wt_s[t]  = 0.5f * (tn - tp);
    }
    __syncthreads();

    const float kk    = k[kidx];
    const float tau0  = tau0p[0];
    const float xmin  = bx[0];
    const float xmax  = bx[N_X - 1];
    const float scale = (float)(N_X - 1) / (xmax - xmin);

    const float* Srow0 = S0 + (size_t)kidx * N_TAU;
    const float* Srow1 = S1 + (size_t)kidx * N_TAU;
    const float* Srow2 = S2 + (size_t)kidx * N_TAU;
    const float* SrowE = SE + (size_t)kidx * N_TAU;

    float accT = 0.0f, accE = 0.0f;

    #pragma unroll 2
    for (int t = wave; t < N_TAU; t += 8) {
        float tt = tau_s[t];
        float wt = wt_s[t];

        float x   = kk * (tau0 - tt);
        float pos = (x - xmin) * scale;
        pos = fminf(fmaxf(pos, 0.0f), (float)(N_X - 1));
        int i0 = (int)pos;                 // pos >= 0 so trunc == floor
        if (i0 > N_X - 2) i0 = N_X - 2;
        float w = pos - (float)i0;

        const float4* row = P + (size_t)i0 * N_ELL + ell;
        float4 ra = row[0];
        float4 rb = row[N_ELL];

        float s0 = Srow0[t], s1 = Srow1[t], s2 = Srow2[t], se = SrowE[t];

        float v0 = fmaf(w, rb.x - ra.x, ra.x);
        float v1 = fmaf(w, rb.y - ra.y, ra.y);
        float v2 = fmaf(w, rb.z - ra.z, ra.z);
        float ve = fmaf(w, rb.w - ra.w, ra.w);

        accT = fmaf(wt, s0 * v0 + s1 * v1 + s2 * v2, accT);
        accE = fmaf(wt, se * ve, accE);
    }

    __shared__ float redT[8][N_ELL];
    __shared__ float redE[8][N_ELL];
    if (lane < N_ELL) { redT[wave][lane] = accT; redE[wave][lane] = accE; }
    __syncthreads();
    if (tid < N_ELL) {
        float sT = 0.0f, sE = 0.0f;
        #pragma unroll
        for (int wv = 0; wv < 8; ++wv) { sT += redT[wv][tid]; sE += redE[wv][tid]; }
        Tl[tid * N_K + kidx] = sT;   // [ell][k] -> coalesced in cl_kernel
        El[tid * N_K + kidx] = sE;
    }
}

// ---------------------------------------------------------------------------
// Fallback (round-1) kernel, used only if ws_size can't fit the packed table.
__global__ __launch_bounds__(256) void tl_el_kernel(
    const float* __restrict__ k, const float* __restrict__ tau,
    const float* __restrict__ tau0p,
    const float* __restrict__ S0, const float* __restrict__ S1,
    const float* __restrict__ S2, const float* __restrict__ SE,
    const float* __restrict__ bx,
    const float* __restrict__ p0, const float* __restrict__ p1,
    const float* __restrict__ p2, const float* __restrict__ pe,
    float* __restrict__ Tl, float* __restrict__ El)
{
    const int kidx = blockIdx.x;
    const int tid  = threadIdx.x;
    const int wave = tid >> 6;
    const int lane = tid & 63;
    const int ell  = (lane < N_ELL) ? lane : (N_ELL - 1);

    const float kk    = k[kidx];
    const float tau0  = tau0p[0];
    const float xmin  = bx[0];
    const float xmax  = bx[N_X - 1];
    const float scale = (float)(N_X - 1) / (xmax - xmin);

    const float* Srow0 = S0 + (size_t)kidx * N_TAU;
    const float* Srow1 = S1 + (size_t)kidx * N_TAU;
    const float* Srow2 = S2 + (size_t)kidx * N_TAU;
    const float* SrowE = SE + (size_t)kidx * N_TAU;

    float accT = 0.0f, accE = 0.0f;

    for (int t = wave; t < N_TAU; t += 4) {
        float tt    = tau[t];
        float tprev = (t > 0)         ? tau[t - 1] : tt;
        float tnext = (t < N_TAU - 1) ? tau[t + 1] : tt;
        float wt    = 0.5f * (tnext - tprev);

        float x   = kk * (tau0 - tt);
        float pos = (x - xmin) * scale;
        pos = fminf(fmaxf(pos, 0.0f), (float)(N_X - 1));
        int i0 = (int)floorf(pos);
        if (i0 > N_X - 2) i0 = N_X - 2;
        float w = pos - (float)i0;

        int base = i0 * N_ELL + ell;
        float y00 = p0[base], y01 = p0[base + N_ELL];
        float y10 = p1[base], y11 = p1[base + N_ELL];
        float y20 = p2[base], y21 = p2[base + N_ELL];
        float ye0 = pe[base], ye1 = pe[base + N_ELL];

        float a0 = fmaf(w, y01 - y00, y00);
        float a1 = fmaf(w, y11 - y10, y10);
        float a2 = fmaf(w, y21 - y20, y20);
        float ae = fmaf(w, ye1 - ye0, ye0);

        float s0 = Srow0[t], s1 = Srow1[t], s2 = Srow2[t], se = SrowE[t];

        float srcT = s0 * a0 + s1 * a1 + s2 * a2;
        accT = fmaf(wt, srcT, accT);
        accE = fmaf(wt, se * ae, accE);
    }

    __shared__ float redT[4][N_ELL];
    __shared__ float redE[4][N_ELL];
    if (lane < N_ELL) { redT[wave][lane] = accT; redE[wave][lane] = accE; }
    __syncthreads();
    if (tid < N_ELL) {
        float sT = (redT[0][tid] + redT[1][tid]) + (redT[2][tid] + redT[3][tid]);
        float sE = (redE[0][tid] + redE[1][tid]) + (redE[2][tid] + redE[3][tid]);
        Tl[tid * N_K + kidx] = sT;
        El[tid * N_K + kidx] = sE;
    }
}

// ---------------------------------------------------------------------------
// Kernel 2: one block per ell. Trapezoid over k with primordial-spectrum weight.
__global__ __launch_bounds__(256) void cl_kernel(
    const float* __restrict__ k,
    const float* __restrict__ Asp, const float* __restrict__ nsp,
    const float* __restrict__ Tl, const float* __restrict__ El,
    float* __restrict__ out)
{
    const int ell = blockIdx.x;
    const int tid = threadIdx.x;
    const float A_s = Asp[0];
    const float n_s = nsp[0];
    const float two_pi2 = 2.0f * (float)M_PI * (float)M_PI;

    float aTT = 0.0f, aEE = 0.0f, aTE = 0.0f;
    for (int i = tid; i < N_K; i += 256) {
        float kv    = k[i];
        float kprev = (i > 0)       ? k[i - 1] : kv;
        float knext = (i < N_K - 1) ? k[i + 1] : kv;
        float dkw   = 0.5f * (knext - kprev);
        float P  = A_s * powf(kv / 0.05f, n_s - 1.0f) * two_pi2 / kv;
        float ww = dkw * P;
        float tl = Tl[(size_t)ell * N_K + i];
        float el = El[(size_t)ell * N_K + i];
        aTT = fmaf(ww * tl, tl, aTT);
        aEE = fmaf(ww * el, el, aEE);
        aTE = fmaf(ww * tl, el, aTE);
    }

    for (int off = 32; off > 0; off >>= 1) {
        aTT += __shfl_down(aTT, off, 64);
        aEE += __shfl_down(aEE, off, 64);
        aTE += __shfl_down(aTE, off, 64);
    }
    __shared__ float red[3][4];
    const int wave = tid >> 6, lane = tid & 63;
    if (lane == 0) { red[0][wave] = aTT; red[1][wave] = aEE; red[2][wave] = aTE; }
    __syncthreads();
    if (tid == 0) {
        const float c = 2.0f / (float)M_PI;
        out[0 * N_ELL + ell] = c * ((red[0][0] + red[0][1]) + (red[0][2] + red[0][3]));
        out[1 * N_ELL + ell] = c * ((red[1][0] + red[1][1]) + (red[1][2] + red[1][3]));
        out[2 * N_ELL + ell] = c * ((red[2][0] + red[2][1]) + (red[2][2] + red[2][3]));
    }
}

extern "C" void kernel_launch(void* const* d_in, const int* in_sizes, int n_in,
                              void* d_out, int out_size, void* d_ws, size_t ws_size,
                              hipStream_t stream) {
    const float* k    = (const float*)d_in[0];
    const float* tau  = (const float*)d_in[1];
    const float* tau0 = (const float*)d_in[2];
    const float* S0   = (const float*)d_in[3];
    const float* S1   = (const float*)d_in[4];
    const float* S2   = (const float*)d_in[5];
    const float* SE   = (const float*)d_in[6];
    const float* bx   = (const float*)d_in[7];
    const float* p0   = (const float*)d_in[8];
    const float* p1   = (const float*)d_in[9];
    const float* p2   = (const float*)d_in[10];
    const float* pe   = (const float*)d_in[11];
    const float* A_s  = (const float*)d_in[12];
    const float* n_s  = (const float*)d_in[13];
    float* out = (float*)d_out;

    const size_t P_bytes    = (size_t)N_X * N_ELL * sizeof(float4);   // 15.36 MB
    const size_t TlEl_bytes = (size_t)N_ELL * N_K * sizeof(float) * 2;

    if (ws_size >= P_bytes + TlEl_bytes) {
        float4* P  = (float4*)d_ws;
        float*  Tl = (float*)((char*)d_ws + P_bytes);
        float*  El = Tl + (size_t)N_ELL * N_K;

        repack_kernel<<<(N_X * N_ELL + 255) / 256, 256, 0, stream>>>(p0, p1, p2, pe, P);
        tl_el_packed<<<N_K, 512, 0, stream>>>(k, tau, tau0, S0, S1, S2, SE, bx,
                                              P, Tl, El);
        cl_kernel<<<N_ELL, 256, 0, stream>>>(k, A_s, n_s, Tl, El, out);
    } else {
        float* Tl = (float*)d_ws;
        float* El = Tl + (size_t)N_ELL * N_K;
        tl_el_kernel<<<N_K, 256, 0, stream>>>(k, tau, tau0, S0, S1, S2, SE, bx,
                                              p0, p1, p2, pe, Tl, El);
        cl_kernel<<<N_ELL, 256, 0, stream>>>(k, A_s, n_s, Tl, El, out);
    }
}

// Round 3
// 143.911 us; speedup vs baseline: 1.4058x; 1.0908x over previous
//
#include <hip/hip_runtime.h>
#include <math.h>

#define N_X   20000
#define N_ELL 48
#define N_K   1024
#define N_TAU 600

// ---------------------------------------------------------------------------
// bf16 helpers (manual RNE pack/unpack; avoids header API variance)
__device__ __forceinline__ unsigned int bf16_rne(float f) {
    unsigned int u = __float_as_uint(f);
    unsigned int r = (u + 0x7FFFu + ((u >> 16) & 1u)) >> 16;   // RNE to bf16
    return r;
}
__device__ __forceinline__ float bf16_lo(unsigned int w) {     // low 16 bits
    return __uint_as_float(w << 16);
}
__device__ __forceinline__ float bf16_hi(unsigned int w) {     // high 16 bits
    return __uint_as_float(w & 0xFFFF0000u);
}

// ---------------------------------------------------------------------------
// Repack four [N_X][N_ELL] fp32 tables into [N_X][N_ELL] bf16x4 (uint2):
//   word x: lo=p0, hi=p1 ; word y: lo=p2, hi=pe.  8 B/entry vs 16 B.
__global__ __launch_bounds__(256) void repack_kernel(
    const float* __restrict__ p0, const float* __restrict__ p1,
    const float* __restrict__ p2, const float* __restrict__ pe,
    uint2* __restrict__ P)
{
    const int total = N_X * N_ELL;
    for (int idx = blockIdx.x * blockDim.x + threadIdx.x; idx < total;
         idx += gridDim.x * blockDim.x) {
        uint2 v;
        v.x = bf16_rne(p0[idx]) | (bf16_rne(p1[idx]) << 16);
        v.y = bf16_rne(p2[idx]) | (bf16_rne(pe[idx]) << 16);
        P[idx] = v;
    }
}

// ---------------------------------------------------------------------------
// Main kernel: one block per k, 512 threads = 8 waves, lane = ell.
// Per-block precompute (i0, w, wt) per tau + stage S rows in LDS, so the hot
// loop is: 2 dwordx2 gathers + LDS reads + FMAs.
__global__ __launch_bounds__(512) void tl_el_packed(
    const float* __restrict__ k, const float* __restrict__ tau,
    const float* __restrict__ tau0p,
    const float* __restrict__ S0, const float* __restrict__ S1,
    const float* __restrict__ S2, const float* __restrict__ SE,
    const float* __restrict__ bx, const uint2* __restrict__ P,
    float* __restrict__ Tl, float* __restrict__ El)
{
    const int kidx = blockIdx.x;
    const int tid  = threadIdx.x;
    const int wave = tid >> 6;
    const int lane = tid & 63;
    const int ell  = (lane < N_ELL) ? lane : (N_ELL - 1);

    __shared__ int   i0_s[N_TAU];
    __shared__ float w_s[N_TAU];
    __shared__ float wt_s[N_TAU];
    __shared__ float S_s[4][N_TAU];

    const float kk    = k[kidx];
    const float tau0  = tau0p[0];
    const float xmin  = bx[0];
    const float xmax  = bx[N_X - 1];
    const float scale = (float)(N_X - 1) / (xmax - xmin);

    // per-tau uniform precompute
    for (int t = tid; t < N_TAU; t += 512) {
        float tt = tau[t];
        float tp = (t > 0)         ? tau[t - 1] : tt;
        float tn = (t < N_TAU - 1) ? tau[t + 1] : tt;
        wt_s[t] = 0.5f * (tn - tp);
        float x   = kk * (tau0 - tt);
        float pos = (x - xmin) * scale;
        pos = fminf(fmaxf(pos, 0.0f), (float)(N_X - 1));
        int i0 = (int)pos;                       // pos >= 0 -> trunc == floor
        if (i0 > N_X - 2) i0 = N_X - 2;
        i0_s[t] = i0;
        w_s[t]  = pos - (float)i0;
    }
    // stage the four source rows for this k
    {
        const float* Srow0 = S0 + (size_t)kidx * N_TAU;
        const float* Srow1 = S1 + (size_t)kidx * N_TAU;
        const float* Srow2 = S2 + (size_t)kidx * N_TAU;
        const float* SrowE = SE + (size_t)kidx * N_TAU;
        for (int i = tid; i < 4 * N_TAU; i += 512) {
            int a = i / N_TAU;
            int t = i - a * N_TAU;
            const float* src = (a == 0) ? Srow0 : (a == 1) ? Srow1
                             : (a == 2) ? Srow2 : SrowE;
            S_s[a][t] = src[t];
        }
    }
    __syncthreads();

    float accT = 0.0f, accE = 0.0f;

    #pragma unroll 4
    for (int t = wave; t < N_TAU; t += 8) {
        int   i0 = i0_s[t];
        float w  = w_s[t];
        float wt = wt_s[t];

        const uint2* row = P + (size_t)i0 * N_ELL + ell;
        uint2 ra = row[0];
        uint2 rb = row[N_ELL];

        float s0 = S_s[0][t], s1 = S_s[1][t], s2 = S_s[2][t], se = S_s[3][t];

        float a0 = bf16_lo(ra.x), a1 = bf16_hi(ra.x);
        float a2 = bf16_lo(ra.y), ae = bf16_hi(ra.y);
        float b0 = bf16_lo(rb.x), b1 = bf16_hi(rb.x);
        float b2 = bf16_lo(rb.y), be = bf16_hi(rb.y);

        float v0 = fmaf(w, b0 - a0, a0);
        float v1 = fmaf(w, b1 - a1, a1);
        float v2 = fmaf(w, b2 - a2, a2);
        float ve = fmaf(w, be - ae, ae);

        accT = fmaf(wt, s0 * v0 + s1 * v1 + s2 * v2, accT);
        accE = fmaf(wt, se * ve, accE);
    }

    __shared__ float redT[8][N_ELL];
    __shared__ float redE[8][N_ELL];
    if (lane < N_ELL) { redT[wave][lane] = accT; redE[wave][lane] = accE; }
    __syncthreads();
    if (tid < N_ELL) {
        float sT = 0.0f, sE = 0.0f;
        #pragma unroll
        for (int wv = 0; wv < 8; ++wv) { sT += redT[wv][tid]; sE += redE[wv][tid]; }
        Tl[tid * N_K + kidx] = sT;   // [ell][k] -> coalesced in cl_kernel
        El[tid * N_K + kidx] = sE;
    }
}

// ---------------------------------------------------------------------------
// Fallback (round-1, fp32 path) if ws can't hold the packed table.
__global__ __launch_bounds__(256) void tl_el_kernel(
    const float* __restrict__ k, const float* __restrict__ tau,
    const float* __restrict__ tau0p,
    const float* __restrict__ S0, const float* __restrict__ S1,
    const float* __restrict__ S2, const float* __restrict__ SE,
    const float* __restrict__ bx,
    const float* __restrict__ p0, const float* __restrict__ p1,
    const float* __restrict__ p2, const float* __restrict__ pe,
    float* __restrict__ Tl, float* __restrict__ El)
{
    const int kidx = blockIdx.x;
    const int tid  = threadIdx.x;
    const int wave = tid >> 6;
    const int lane = tid & 63;
    const int ell  = (lane < N_ELL) ? lane : (N_ELL - 1);

    const float kk    = k[kidx];
    const float tau0  = tau0p[0];
    const float xmin  = bx[0];
    const float xmax  = bx[N_X - 1];
    const float scale = (float)(N_X - 1) / (xmax - xmin);

    const float* Srow0 = S0 + (size_t)kidx * N_TAU;
    const float* Srow1 = S1 + (size_t)kidx * N_TAU;
    const float* Srow2 = S2 + (size_t)kidx * N_TAU;
    const float* SrowE = SE + (size_t)kidx * N_TAU;

    float accT = 0.0f, accE = 0.0f;

    for (int t = wave; t < N_TAU; t += 4) {
        float tt    = tau[t];
        float tprev = (t > 0)         ? tau[t - 1] : tt;
        float tnext = (t < N_TAU - 1) ? tau[t + 1] : tt;
        float wt    = 0.5f * (tnext - tprev);

        float x   = kk * (tau0 - tt);
        float pos = (x - xmin) * scale;
        pos = fminf(fmaxf(pos, 0.0f), (float)(N_X - 1));
        int i0 = (int)floorf(pos);
        if (i0 > N_X - 2) i0 = N_X - 2;
        float w = pos - (float)i0;

        int base = i0 * N_ELL + ell;
        float y00 = p0[base], y01 = p0[base + N_ELL];
        float y10 = p1[base], y11 = p1[base + N_ELL];
        float y20 = p2[base], y21 = p2[base + N_ELL];
        float ye0 = pe[base], ye1 = pe[base + N_ELL];

        float a0 = fmaf(w, y01 - y00, y00);
        float a1 = fmaf(w, y11 - y10, y10);
        float a2 = fmaf(w, y21 - y20, y20);
        float ae = fmaf(w, ye1 - ye0, ye0);

        float s0 = Srow0[t], s1 = Srow1[t], s2 = Srow2[t], se = SrowE[t];

        float srcT = s0 * a0 + s1 * a1 + s2 * a2;
        accT = fmaf(wt, srcT, accT);
        accE = fmaf(wt, se * ae, accE);
    }

    __shared__ float redT[4][N_ELL];
    __shared__ float redE[4][N_ELL];
    if (lane < N_ELL) { redT[wave][lane] = accT; redE[wave][lane] = accE; }
    __syncthreads();
    if (tid < N_ELL) {
        float sT = (redT[0][tid] + redT[1][tid]) + (redT[2][tid] + redT[3][tid]);
        float sE = (redE[0][tid] + redE[1][tid]) + (redE[2][tid] + redE[3][tid]);
        Tl[tid * N_K + kidx] = sT;
        El[tid * N_K + kidx] = sE;
    }
}

// ---------------------------------------------------------------------------
// Kernel 2: one block per ell. Trapezoid over k with primordial-spectrum weight.
__global__ __launch_bounds__(256) void cl_kernel(
    const float* __restrict__ k,
    const float* __restrict__ Asp, const float* __restrict__ nsp,
    const float* __restrict__ Tl, const float* __restrict__ El,
    float* __restrict__ out)
{
    const int ell = blockIdx.x;
    const int tid = threadIdx.x;
    const float A_s = Asp[0];
    const float n_s = nsp[0];
    const float two_pi2 = 2.0f * (float)M_PI * (float)M_PI;

    float aTT = 0.0f, aEE = 0.0f, aTE = 0.0f;
    for (int i = tid; i < N_K; i += 256) {
        float kv    = k[i];
        float kprev = (i > 0)       ? k[i - 1] : kv;
        float knext = (i < N_K - 1) ? k[i + 1] : kv;
        float dkw   = 0.5f * (knext - kprev);
        float P  = A_s * powf(kv / 0.05f, n_s - 1.0f) * two_pi2 / kv;
        float ww = dkw * P;
        float tl = Tl[(size_t)ell * N_K + i];
        float el = El[(size_t)ell * N_K + i];
        aTT = fmaf(ww * tl, tl, aTT);
        aEE = fmaf(ww * el, el, aEE);
        aTE = fmaf(ww * tl, el, aTE);
    }

    for (int off = 32; off > 0; off >>= 1) {
        aTT += __shfl_down(aTT, off, 64);
        aEE += __shfl_down(aEE, off, 64);
        aTE += __shfl_down(aTE, off, 64);
    }
    __shared__ float red[3][4];
    const int wave = tid >> 6, lane = tid & 63;
    if (lane == 0) { red[0][wave] = aTT; red[1][wave] = aEE; red[2][wave] = aTE; }
    __syncthreads();
    if (tid == 0) {
        const float c = 2.0f / (float)M_PI;
        out[0 * N_ELL + ell] = c * ((red[0][0] + red[0][1]) + (red[0][2] + red[0][3]));
        out[1 * N_ELL + ell] = c * ((red[1][0] + red[1][1]) + (red[1][2] + red[1][3]));
        out[2 * N_ELL + ell] = c * ((red[2][0] + red[2][1]) + (red[2][2] + red[2][3]));
    }
}

extern "C" void kernel_launch(void* const* d_in, const int* in_sizes, int n_in,
                              void* d_out, int out_size, void* d_ws, size_t ws_size,
                              hipStream_t stream) {
    const float* k    = (const float*)d_in[0];
    const float* tau  = (const float*)d_in[1];
    const float* tau0 = (const float*)d_in[2];
    const float* S0   = (const float*)d_in[3];
    const float* S1   = (const float*)d_in[4];
    const float* S2   = (const float*)d_in[5];
    const float* S2_  = (const float*)d_in[5];
    const float* SE   = (const float*)d_in[6];
    const float* bx   = (const float*)d_in[7];
    const float* p0   = (const float*)d_in[8];
    const float* p1   = (const float*)d_in[9];
    const float* p2   = (const float*)d_in[10];
    const float* pe   = (const float*)d_in[11];
    const float* A_s  = (const float*)d_in[12];
    const float* n_s  = (const float*)d_in[13];
    float* out = (float*)d_out;
    (void)S2_;

    const size_t P_bytes    = (size_t)N_X * N_ELL * sizeof(uint2);    // 7.68 MB
    const size_t TlEl_bytes = (size_t)N_ELL * N_K * sizeof(float) * 2;

    if (ws_size >= P_bytes + TlEl_bytes) {
        uint2* P  = (uint2*)d_ws;
        float* Tl = (float*)((char*)d_ws + P_bytes);
        float* El = Tl + (size_t)N_ELL * N_K;

        repack_kernel<<<(N_X * N_ELL + 255) / 256, 256, 0, stream>>>(p0, p1, p2, pe, P);
        tl_el_packed<<<N_K, 512, 0, stream>>>(k, tau, tau0, S0, S1, S2, SE, bx,
                                              P, Tl, El);
        cl_kernel<<<N_ELL, 256, 0, stream>>>(k, A_s, n_s, Tl, El, out);
    } else {
        float* Tl = (float*)d_ws;
        float* El = Tl + (size_t)N_ELL * N_K;
        tl_el_kernel<<<N_K, 256, 0, stream>>>(k, tau, tau0, S0, S1, S2, SE, bx,
                                              p0, p1, p2, pe, Tl, El);
        cl_kernel<<<N_ELL, 256, 0, stream>>>(k, A_s, n_s, Tl, El, out);
    }
}